// Round 7
// baseline (396.504 us; speedup 1.0000x reference)
//
#include <hip/hip_runtime.h>

// out[b, f*TIME+t, e] = x[b, f*TIME+t, e] + pe_1d[f, e] + pe_1d[t, e]
// B=4, FREQ=256, TIME=512, E=512, fp32.
//
// Structure (rounds 3-5, kept): block owns a CONTIGUOUS chunk (32 rows);
// e4/f/b constant per thread/block; pf hoisted; nt on the one-touch x/out
// streams; fine grid (16384 blocks) for tail smoothing; unroll 8.
//
// Round 6 change: eliminate the per-iteration pe[t] load. pe row t holds
// (sin t*d_j, cos t*d_j) pairs and t advances by exactly 2/iter, so
//   pt(t+2) = R(2*d_j) * pt(t),  and row 2 of the table IS (sin 2d, cos 2d).
// Load pf, pt(t0), rot=pe[2] once per thread (exact table values), then
// advance pt with 8 FMAs/iter. Inner loop = nt load + adds + nt store:
// memory-identical to a pure streaming copy. Rotation error over <=30
// steps ~3e-6 << 0.147 threshold.

typedef float f32x4 __attribute__((ext_vector_type(4)));

constexpr int  B_    = 4;
constexpr int  FREQ_ = 256;
constexpr int  TIME_ = 512;
constexpr int  E_    = 512;
constexpr int  E4    = E_ / 4;                 // 128 float4 per row
constexpr int  ROWS  = FREQ_ * TIME_;          // 131072 rows per batch
constexpr long N4T   = (long)B_ * ROWS * E4;   // 2^26 total float4

constexpr int BLOCK = 256;
constexpr int ITERS = 16;
constexpr int CHUNK = BLOCK * ITERS;           // 4096 float4 = 32 rows per block
constexpr int GRID  = (int)(N4T / CHUNK);      // 16384 blocks

static_assert(CHUNK % E4 == 0, "chunk row-aligned");
static_assert((CHUNK / E4) <= TIME_ && TIME_ % (CHUNK / E4) == 0, "f const per block");
static_assert(((long)ROWS * E4) % CHUNK == 0, "b const per block");

__global__ void __launch_bounds__(BLOCK)
pe2d_add_kernel(const f32x4* __restrict__ x,
                const f32x4* __restrict__ pe,
                f32x4* __restrict__ out)
{
    const int base    = blockIdx.x * CHUNK;          // < 2^26, fits int
    const int tid     = threadIdx.x;
    const int e4      = tid & (E4 - 1);
    const int dt      = tid >> 7;                    // 0 or 1: second row half
    const int rowbase = (base >> 7) & (ROWS - 1);    // row within batch
    const int f       = rowbase >> 9;                // constant per block
    const int t0      = (rowbase & (TIME_ - 1)) + dt;

    // one-time table loads (exact float32 table values)
    const f32x4 pf  = pe[f  * E4 + e4];              // freq component
    f32x4       pt  = pe[t0 * E4 + e4];              // time component at t0
    const f32x4 rot = pe[2  * E4 + e4];              // (sin 2d0, cos 2d0, sin 2d1, cos 2d1)

    int i = base + tid;

    #pragma unroll 8
    for (int it = 0; it < ITERS; ++it) {
        f32x4 v = __builtin_nontemporal_load(&x[i]); // one-touch stream
        v = v + pf + pt;
        __builtin_nontemporal_store(v, &out[i]);     // one-touch stream
        i += BLOCK;                                  // +4 KB per iteration

        // advance time component: t -> t+2 via 2D rotation per (sin,cos) pair
        //   s' = s*cos2d + c*sin2d ; c' = c*cos2d - s*sin2d
        f32x4 np;
        np.x = pt.x * rot.y + pt.y * rot.x;
        np.y = pt.y * rot.y - pt.x * rot.x;
        np.z = pt.z * rot.w + pt.w * rot.z;
        np.w = pt.w * rot.w - pt.z * rot.z;
        pt = np;
    }
}

extern "C" void kernel_launch(void* const* d_in, const int* in_sizes, int n_in,
                              void* d_out, int out_size, void* d_ws, size_t ws_size,
                              hipStream_t stream)
{
    const f32x4* x  = (const f32x4*)d_in[0];   // (B, FREQ*TIME, E) fp32
    const f32x4* pe = (const f32x4*)d_in[1];   // (512, E) fp32
    f32x4* out = (f32x4*)d_out;

    pe2d_add_kernel<<<GRID, BLOCK, 0, stream>>>(x, pe, out);
}